// Round 12
// baseline (152.378 us; speedup 1.0000x reference)
//
#include <hip/hip_runtime.h>
#include <math.h>

#define PH 7
#define PW 7
#define B_ 4
#define C_ 256
#define H_ 50
#define W_ 50
#define R_ 256
#define S_ (H_ * W_)     // 2500
#define NCELL (PH * PW)  // 49
#define THREADS 512
#define REP 3            // DIAGNOSTIC: repeat gather phase so this kernel tops
                         // the rocprof table with real counters. dur ~= stage +
                         // 3x gather; stores idempotent -> output correct.

// Single dispatch, original (B,C,H,W) layout. Block = (b,c): 10 KB plane
// staged in LDS (features read exactly once); pooling = LDS gathers.
// IDENTICAL to round-11 except the REP loop around the gather phase.
__global__ void __launch_bounds__(THREADS, 8)
roi_pool_plane(const float* __restrict__ features, const int* __restrict__ rois,
               float* __restrict__ out) {
    __shared__ __align__(16) float pl[S_];   // 10 KB plane
    __shared__ int4 geom[R_];                // x1,y1,h,w of matching rois
    __shared__ int  rlist[R_];               // their original indices
    __shared__ int  nmatch;

    const int bx = blockIdx.x;
    const int c  = bx & 255;                 // 0..255
    const int b  = bx >> 8;                  // 0..3
    const int tid = threadIdx.x;

    if (tid == 0) nmatch = 0;
    __syncthreads();

    // stage plane (625 float4, coalesced; plane base 10000B -> 16B aligned)
    {
        const float4* src = (const float4*)(features + ((size_t)b * C_ + c) * S_);
        float4* dst = (float4*)pl;
        for (int i = tid; i < S_ / 4; i += THREADS) dst[i] = src[i];
    }

    // compact this batch's rois (order irrelevant -> LDS atomic)
    if (tid < R_) {
        const int* roi = rois + tid * 5;
        if (roi[0] == b) {
            const int x1 = roi[1] >> 4;      // floor(v/16), v in [0,800)
            const int y1 = roi[2] >> 4;
            const int x2 = roi[3] >> 4;
            const int y2 = roi[4] >> 4;
            const int pos = atomicAdd(&nmatch, 1);
            geom[pos]  = make_int4(x1, y1, y2 - y1 + 1, x2 - x1 + 1);
            rlist[pos] = tid;
        }
    }
    __syncthreads();

    const int total = nmatch * NCELL;

    #pragma unroll 1
    for (int rep = 0; rep < REP; ++rep) {
        for (int i = tid; i < total; i += THREADS) {
            const int j    = i / NCELL;          // const divisor -> magic mul
            const int cell = i - j * NCELL;
            const int4 g   = geom[j];            // x1,y1,h,w
            const int ph   = cell / PW;          // magic mul
            const int pw   = cell - ph * PW;

            const int sh = g.y + (ph * g.z) / PH;
            const int eh = g.y + ((ph + 1) * g.z + PH - 1) / PH;   // <= 50
            const int sw = g.x + (pw * g.w) / PW;
            const int ew = g.x + ((pw + 1) * g.w + PW - 1) / PW;   // <= 50

            float m = -INFINITY;
            for (int y = sh; y < eh; ++y) {
                const float* prow = pl + y * W_;
                for (int x = sw; x < ew; ++x) m = fmaxf(m, prow[x]);
            }

            out[((size_t)rlist[j] * C_ + c) * NCELL + cell] = m;
        }
        asm volatile("" ::: "memory");       // block cross-rep load CSE
    }
}

extern "C" void kernel_launch(void* const* d_in, const int* in_sizes, int n_in,
                              void* d_out, int out_size, void* d_ws, size_t ws_size,
                              hipStream_t stream) {
    const float* features = (const float*)d_in[0];
    const int*   rois     = (const int*)d_in[1];
    float*       out      = (float*)d_out;
    (void)d_ws; (void)ws_size;

    roi_pool_plane<<<B_ * C_, THREADS, 0, stream>>>(features, rois, out);
}

// Round 13
// 95.285 us; speedup vs baseline: 1.5992x; 1.5992x over previous
//
#include <hip/hip_runtime.h>
#include <math.h>

#define PH 7
#define PW 7
#define B_ 4
#define C_ 256
#define H_ 50
#define W_ 50
#define R_ 256
#define S_ (H_ * W_)     // 2500
#define NCELL (PH * PW)  // 49
#define THREADS 512

// Single dispatch, original (B,C,H,W) layout. Block = (b,c): 10 KB plane in
// LDS (features read exactly once). R12 counters showed the old per-thread
// divergent gather was issue-bound (VALUBusy 80%, ~30x instr overhead from
// per-lane trip-count divergence + serial chains, VGPR=12).
// NEW gather: wave = roi, lane = cell. Adaptive-pool band sizes differ by
// <=2 across cells, so loops run to wave-uniform bounds (readfirstlane ->
// scalar loops, NO divergence) with reads clamped via min(k, kmax-1) —
// duplicate reads are max-safe (R0-proven dup trick). ~5 instr/px, ~16 px
// per cell, all 49 cells of a roi in one wave pass.
__global__ void __launch_bounds__(THREADS, 8)
roi_pool_plane(const float* __restrict__ features, const int* __restrict__ rois,
               float* __restrict__ out) {
    __shared__ __align__(16) float pl[S_];   // 10 KB plane
    __shared__ int4 geom[R_];                // x1,y1,h,w of matching rois
    __shared__ int  rlist[R_];               // their original indices
    __shared__ int  nmatch;

    const int bx = blockIdx.x;
    const int c  = bx & 255;                 // 0..255
    const int b  = bx >> 8;                  // 0..3
    const int tid  = threadIdx.x;
    const int wid  = tid >> 6;               // 0..7
    const int lane = tid & 63;

    if (tid == 0) nmatch = 0;
    __syncthreads();

    // stage plane (625 float4, coalesced; plane base 10000B -> 16B aligned)
    {
        const float4* src = (const float4*)(features + ((size_t)b * C_ + c) * S_);
        float4* dst = (float4*)pl;
        for (int i = tid; i < S_ / 4; i += THREADS) dst[i] = src[i];
    }

    // compact this batch's rois (order irrelevant -> LDS atomic)
    if (tid < R_) {
        const int* roi = rois + tid * 5;
        if (roi[0] == b) {
            const int x1 = roi[1] >> 4;      // floor(v/16), v in [0,800)
            const int y1 = roi[2] >> 4;
            const int x2 = roi[3] >> 4;
            const int y2 = roi[4] >> 4;
            const int pos = atomicAdd(&nmatch, 1);
            geom[pos]  = make_int4(x1, y1, y2 - y1 + 1, x2 - x1 + 1);
            rlist[pos] = tid;
        }
    }
    __syncthreads();

    const int nm = __builtin_amdgcn_readfirstlane(nmatch);

    // lane -> cell (lanes 49..63 duplicate cell 48, don't store)
    const unsigned l = (lane < 48) ? lane : 48;
    const unsigned p = l / 7u;               // magic mul
    const unsigned q = l - p * 7u;

    for (int j = wid; j < nm; j += THREADS / 64) {
        const int4 g = geom[j];              // broadcast LDS read
        const unsigned x1 = g.x, y1 = g.y, h = g.z, w = g.w;

        const unsigned sh = y1 + (p * h) / 7u;
        const unsigned eh = y1 + ((p + 1) * h + 6u) / 7u;
        const unsigned sw = x1 + (q * w) / 7u;
        const unsigned ew = x1 + ((q + 1) * w + 6u) / 7u;
        const int khm1 = (int)(eh - sh) - 1;          // >= 0
        const int kwm1 = (int)(ew - sw) - 1;
        const int base = (int)(sh * W_ + sw);

        // wave-uniform loop bounds (scalar): max band size = floor(h/7)+2
        const int khMax = __builtin_amdgcn_readfirstlane((int)(h / 7u)) + 2;
        const int kwMax = __builtin_amdgcn_readfirstlane((int)(w / 7u)) + 2;

        float m = -INFINITY;
        for (int ky = 0; ky < khMax; ++ky) {          // scalar loop, no diverge
            const int rowa = base + min(ky, khm1) * W_;
            for (int kx = 0; kx < kwMax; ++kx) {      // scalar loop
                m = fmaxf(m, pl[rowa + min(kx, kwm1)]);   // clamped: max-safe
            }
        }

        if (lane < NCELL)                     // 49 contiguous floats per wave
            out[((size_t)rlist[j] * C_ + c) * NCELL + lane] = m;
    }
}

extern "C" void kernel_launch(void* const* d_in, const int* in_sizes, int n_in,
                              void* d_out, int out_size, void* d_ws, size_t ws_size,
                              hipStream_t stream) {
    const float* features = (const float*)d_in[0];
    const int*   rois     = (const int*)d_in[1];
    float*       out      = (float*)d_out;
    (void)d_ws; (void)ws_size;

    roi_pool_plane<<<B_ * C_, THREADS, 0, stream>>>(features, rois, out);
}